// Round 12
// baseline (144.780 us; speedup 1.0000x reference)
//
#include <hip/hip_runtime.h>

#define WW 320           // input width/height
#define OWID 314         // output cols
#define OHEI 314         // output rows
#define BB 64            // batch
#define CW 58            // output cols OWNED per wave (lanes 58..63 = halo)
#define NCW 6            // col-waves to cover 314 cols (6*58 = 348)
#define BROWS 40         // output rows per band
#define NBAND 8          // 8*40 = 320 >= 314; tail masked
#define BPB 2            // bands per block
#define WPB (NCW * BPB)  // 12 waves per block
#define NTH (WPB * 64)   // 768 threads
#define NBLK (BB * NBAND / BPB)   // 64*4 = 256 blocks = exactly 1/CU

// One row's 4 coalesced scalar loads into group buffer BUF (a or b).
#define LOADR(BUF, G7, K_)                                                    \
  {                                                                           \
    const int rr  = min(r0 + (G7) + (K_), WW - 1);  /* clamp; tail masked */  \
    const int off = rr * WW;                        /* wave-uniform */        \
    BUF##x0[K_] = X0[off]; BUF##x1[K_] = X1[off];                             \
    BUF##y0[K_] = Y0[off]; BUF##y1[K_] = Y1[off];                             \
  }

// Issue a whole 7-row group (28 loads) into BUF.
#define LOADG(BUF, G7)                                                        \
  LOADR(BUF, G7, 0) LOADR(BUF, G7, 1) LOADR(BUF, G7, 2) LOADR(BUF, G7, 3)    \
  LOADR(BUF, G7, 4) LOADR(BUF, G7, 5) LOADR(BUF, G7, 6)

// One input row step from BUF: vertical ring of 4 combined moments,
// horizontal 7-tap across lanes via shfl tree (bit-exact since R9).
// K_ literal 0..6 and G7 % 7 == 0  =>  ring slot == K_ (static).
#define BODY(BUF, G7, K_)                                                     \
  {                                                                           \
    const float x0 = BUF##x0[K_], x1 = BUF##x1[K_];                           \
    const float y0 = BUF##y0[K_], y1 = BUF##y1[K_];                           \
    const float px  = x0 + x1;                                                \
    const float py  = y0 + y1;                                                \
    const float p2  = x0 * x0 + x1 * x1 + y0 * y0 + y1 * y1;                  \
    const float pxy = x0 * y0 + x1 * y1;                                      \
    V0 += px  - ring[K_][0]; ring[K_][0] = px;                                \
    V1 += py  - ring[K_][1]; ring[K_][1] = py;                                \
    V2 += p2  - ring[K_][2]; ring[K_][2] = p2;                                \
    V3 += pxy - ring[K_][3]; ring[K_][3] = pxy;                               \
    const int i_ = (G7) + (K_);                                               \
    const int t  = r0 + i_ - 6;               /* output row */                \
    if (i_ >= 6 && t < tmax) {                /* wave-uniform mask */         \
      float b0 = V0 + __shfl_down(V0, 1, 64);                                 \
      float b1 = V1 + __shfl_down(V1, 1, 64);                                 \
      float b2 = V2 + __shfl_down(V2, 1, 64);                                 \
      float b3 = V3 + __shfl_down(V3, 1, 64);                                 \
      float q0 = b0 + __shfl_down(b0, 2, 64);                                 \
      float q1 = b1 + __shfl_down(b1, 2, 64);                                 \
      float q2 = b2 + __shfl_down(b2, 2, 64);                                 \
      float q3 = b3 + __shfl_down(b3, 2, 64);                                 \
      float H0 = q0 + __shfl_down(b0, 4, 64) + __shfl_down(V0, 6, 64);        \
      float H1 = q1 + __shfl_down(b1, 4, 64) + __shfl_down(V1, 6, 64);        \
      float H2 = q2 + __shfl_down(b2, 4, 64) + __shfl_down(V2, 6, 64);        \
      float H3 = q3 + __shfl_down(b3, 4, 64) + __shfl_down(V3, 6, 64);        \
      const float ux  = H0 * inv, uy = H1 * inv;                              \
      const float u2  = H2 * inv, uxy = H3 * inv;                             \
      const float vxy = cn * (uxy - ux * uy);                                 \
      const float v2m = cn * (u2 - ux * ux - uy * uy);   /* vx + vy */        \
      const float A1  = 2.0f * ux * uy + C1;                                  \
      const float A2  = 2.0f * vxy + C2;                                      \
      const float B1  = ux * ux + uy * uy + C1;                               \
      const float B2  = v2m + C2;                                             \
      ssum += cmf * (A1 * A2) / (B1 * B2);   /* halo/dup lanes masked */      \
    }                                                                         \
  }

#define BODYG(BUF, G7)                                                        \
  BODY(BUF, G7, 0) BODY(BUF, G7, 1) BODY(BUF, G7, 2) BODY(BUF, G7, 3)        \
  BODY(BUF, G7, 4) BODY(BUF, G7, 5) BODY(BUF, G7, 6)

// Transposed (one output column per thread), 12 co-resident waves per block
// (3/SIMD — R11-proven), PLUS ping-pong group prefetch: group g+1's 28 loads
// are in flight while group g's 7 bodies compute (counted-vmcnt pattern, the
// missing piece that left VALUBusy at 37% in R11).
__global__ __launch_bounds__(NTH, 1) void ssim_main(
    const float* __restrict__ X, const float* __restrict__ Y,
    const float* __restrict__ dr, double* __restrict__ acc,
    unsigned* __restrict__ counter, float* __restrict__ out)
{
    const int w    = threadIdx.x >> 6;        // wave in block (0..11)
    const int lane = threadIdx.x & 63;
    const int b    = blockIdx.x >> 2;         // image
    const int pair = blockIdx.x & 3;          // band pair
    const int band = pair * BPB + (w / NCW);  // this wave's band (0..7)
    const int r0   = band * BROWS;            // first output row of band
    const int tmax = min(r0 + BROWS, OHEI);   // band-exclusive output rows

    int c = (w % NCW) * CW + lane;            // column this lane loads
    const float cmf = (lane < CW && c < OWID) ? 1.0f : 0.0f;  // owner mask
    if (c > WW - 1) c = WW - 1;               // clamp halo loads in-bounds

    const size_t plane = (size_t)WW * WW;
    const float* X0 = X + (size_t)b * 2 * plane + c;
    const float* X1 = X0 + plane;
    const float* Y0 = Y + (size_t)b * 2 * plane + c;
    const float* Y1 = Y0 + plane;

    const float d  = dr[b];
    const float C1 = (0.01f * d) * (0.01f * d);
    const float C2 = (0.03f * d) * (0.03f * d);
    const float inv = 1.0f / 49.0f;
    const float cn  = 49.0f / 48.0f;

    float ring[7][4];                         // 28 regs
    #pragma unroll
    for (int k = 0; k < 7; ++k) {
        ring[k][0] = 0.0f; ring[k][1] = 0.0f;
        ring[k][2] = 0.0f; ring[k][3] = 0.0f;
    }
    float V0 = 0.0f, V1 = 0.0f, V2 = 0.0f, V3 = 0.0f;
    float ssum = 0.0f;

    // Ping-pong group buffers (28 regs each): a = even groups, b = odd.
    float ax0[7], ax1[7], ay0[7], ay1[7];
    float bx0[7], bx1[7], by0[7], by1[7];

    // 49 row-steps = 7 groups of 7 (46 live rows + 3 masked by tmax).
    // Prologue: group 0 -> A. Each rolled iteration handles two groups with
    // the next group's loads always in flight (buffer names static; ring
    // slots literal; no full-unroll live-range blowup).
    LOADG(a, 0)
    #pragma unroll 1
    for (int j14 = 0; j14 < 42; j14 += 14) {
        LOADG(b, j14 + 7)                     // prefetch odd group
        BODYG(a, j14)                         // consume even group
        LOADG(a, j14 + 14)                    // prefetch next even group
        BODYG(b, j14 + 7)                     // consume odd group
    }
    BODYG(a, 42)                              // tail group g6

    // ---- reduction: wave shuffle (double) -> LDS -> one atomic per block ----
    double local = (double)ssum;
    #pragma unroll
    for (int off = 32; off > 0; off >>= 1)
        local += __shfl_down(local, off, 64);
    __shared__ double wsum[WPB];
    if (lane == 0) wsum[w] = local;
    __syncthreads();
    if (threadIdx.x == 0) {
        double tot = 0.0;
        #pragma unroll
        for (int k = 0; k < WPB; ++k) tot += wsum[k];
        atomicAdd(acc, tot);
        __threadfence();
        unsigned ticket = atomicAdd(counter, 1u);
        if (ticket == NBLK - 1) {
            double stot = atomicAdd(acc, 0.0);   // device-scope coherent read
            const double N = (double)BB * (double)OHEI * (double)OWID;
            out[0] = (float)(1.0 - stot / N);
        }
    }
}

extern "C" void kernel_launch(void* const* d_in, const int* in_sizes, int n_in,
                              void* d_out, int out_size, void* d_ws, size_t ws_size,
                              hipStream_t stream)
{
    const float* X  = (const float*)d_in[0];
    const float* Y  = (const float*)d_in[1];
    const float* dr = (const float*)d_in[2];
    // d_in[3] is the box kernel w (all 1/49) — folded into constants.
    double*   acc     = (double*)d_ws;
    unsigned* counter = (unsigned*)((char*)d_ws + 8);
    float*    out     = (float*)d_out;

    hipMemsetAsync(d_ws, 0, 16, stream);
    ssim_main<<<dim3(NBLK), dim3(NTH), 0, stream>>>(X, Y, dr, acc, counter, out);
}